// Round 9
// baseline (40.239 us; speedup 1.0000x reference)
//
#include <hip/hip_runtime.h>
#include <utility>
#include <cmath>

// Problem constants (fixed by the reference setup)
constexpr int T = 2048;
constexpr int B = 8;
constexpr int C = 1024;
constexpr int H = 16;
constexpr int K = 31;
constexpr int PAD = 15;            // PADDING_L
constexpr int NBC = B * C;         // 8192 = t-stride in elements; (b,c) contiguous
constexpr int BLOCK = 64;          // ONE wave per block: no barriers anywhere
constexpr int TT = 32;             // t-outputs per thread
constexpr int WIN = TT + K - 1;    // 62 rows needed
constexpr int ROWSP = 64;          // staged rows (padded to 16 x 4-row groups)
constexpr int NG = ROWSP / 4;      // 16 global_load_lds dwordx4 per wave

// One tap: KK compile-time -> w[KK] stays in SGPR, xv[i+KK] statically-indexed reg.
template <int KK>
__device__ __forceinline__ void tap(float (&acc)[TT], const float (&xv)[WIN], float wk) {
#pragma unroll
    for (int i = 0; i < TT; ++i)
        acc[i] = fmaf(wk, xv[i + KK], acc[i]);
}

template <int... Ks>
__device__ __forceinline__ void all_taps(float (&acc)[TT], const float (&xv)[WIN],
                                         const float (&w)[K],
                                         std::integer_sequence<int, Ks...>) {
    (tap<Ks>(acc, xv, w[Ks]), ...);
}

// Broadcast tap k from lane k to all lanes as wave-uniform (SGPR) values
// (v_readlane_b32 with literal lane index).
template <int... Ks>
__device__ __forceinline__ void bcast_taps(float (&w)[K], float v,
                                           std::integer_sequence<int, Ks...>) {
    ((w[Ks] = __int_as_float(__builtin_amdgcn_readlane(__float_as_int(v), Ks))), ...);
}

// async global->LDS, 16 bytes/lane: LDS dest = wave-uniform base + lane*16
// (4 consecutive rows of 64 floats per instruction); global source per-lane.
__device__ __forceinline__ void gld_lds_b128(const float* gsrc, float* ldst) {
    __builtin_amdgcn_global_load_lds(
        (const __attribute__((address_space(1))) unsigned int*)gsrc,
        (__attribute__((address_space(3))) unsigned int*)ldst,
        16, 0, 0);
}

__global__ __launch_bounds__(BLOCK, 4) void lconv_tbc_kernel(
    const float* __restrict__ x,      // (T, B, C)
    const float* __restrict__ wgt,    // (H, 1, K)
    const float* __restrict__ bias,   // (C)
    const float* __restrict__ zbuf,   // >=256B of zeros (d_ws)
    float* __restrict__ out)          // (T, B, C)
{
    __shared__ float xs[ROWSP * BLOCK];   // 64 rows x 64 cols x 4B = 16 KB (private to this wave)

    const int lane = threadIdx.x;                 // one wave per block
    const int bc0  = blockIdx.x * BLOCK;          // head-aligned (64 cols = one head)
    const int c    = (bc0 + lane) & (C - 1);
    const int t0   = blockIdx.y * TT;
    const int tstart = t0 - PAD;

    // ---- stage the private 62(+2 pad)-row window: 16 async DMA ops, all in flight ----
    const int lane_row = lane >> 4;               // 0..3
    const int lane_col = (lane & 15) * 4;         // float col within row
    const ptrdiff_t lane_off = (ptrdiff_t)lane_row * NBC + lane_col;
    const float* zsrc = zbuf + lane_col;          // 16B-aligned zero source
    #pragma unroll
    for (int g = 0; g < NG; ++g) {
        const int tg0 = tstart + 4 * g;
        const int tg  = tg0 + lane_row;           // this lane's global row
        const float* src = x + (ptrdiff_t)tg0 * NBC + bc0 + lane_off;
        const float* p   = ((unsigned)tg < (unsigned)T) ? src : zsrc;
        gld_lds_b128(p, &xs[g * 4 * BLOCK]);
    }

    // ---- softmax of this head's taps, under the DMA latency ----
    const int head = c >> 6;                      // wave-uniform
    float raw = (lane < K) ? wgt[head * K + lane] : -INFINITY;
    float m = raw;
    #pragma unroll
    for (int off = 32; off >= 1; off >>= 1) m = fmaxf(m, __shfl_xor(m, off));
    float e = (lane < K) ? expf(raw - m) : 0.0f;
    float s = e;
    #pragma unroll
    for (int off = 32; off >= 1; off >>= 1) s += __shfl_xor(s, off);
    const float myw = e / s;

    float w[K];
    bcast_taps(w, myw, std::make_integer_sequence<int, K>{});   // 31x v_readlane -> SGPRs
    const float bb = bias[c];

    // single drain of the 16 DMA ops; same-wave vmcnt ordering, no barrier needed
    asm volatile("s_waitcnt vmcnt(0)" ::: "memory");
    __builtin_amdgcn_sched_barrier(0);

    // ---- window from LDS: 62 conflict-free ds_read_b32 (stride 256B, lane-linear) ----
    float xv[WIN];
    #pragma unroll
    for (int j = 0; j < WIN; ++j)
        xv[j] = xs[j * BLOCK + lane];

    // ---- 31 x 32 FMAs, every index compile-time ----
    float acc[TT];
    #pragma unroll
    for (int i = 0; i < TT; ++i) acc[i] = 0.0f;
    all_taps(acc, xv, w, std::make_integer_sequence<int, K>{});

    // ---- epilogue: bias + coalesced nontemporal stores ----
    float* op = out + (size_t)t0 * NBC + bc0 + lane;
    #pragma unroll
    for (int i = 0; i < TT; ++i)
        __builtin_nontemporal_store(acc[i] + bb, &op[(size_t)i * NBC]);
}

extern "C" void kernel_launch(void* const* d_in, const int* in_sizes, int n_in,
                              void* d_out, int out_size, void* d_ws, size_t ws_size,
                              hipStream_t stream) {
    const float* x    = (const float*)d_in[0];
    const float* wgt  = (const float*)d_in[1];
    const float* bias = (const float*)d_in[2];
    float* out        = (float*)d_out;
    float* zbuf       = (float*)d_ws;

    hipMemsetAsync(zbuf, 0, 256, stream);   // zero source for out-of-range halo rows

    dim3 grid(NBC / BLOCK, T / TT);         // (128, 64) = 8192 single-wave blocks
    lconv_tbc_kernel<<<grid, dim3(BLOCK), 0, stream>>>(x, wgt, bias, zbuf, out);
}

// Round 10
// 35.245 us; speedup vs baseline: 1.1417x; 1.1417x over previous
//
#include <hip/hip_runtime.h>
#include <utility>
#include <cmath>

// Problem constants (fixed by the reference setup)
constexpr int T = 2048;
constexpr int C = 1024;
constexpr int K = 31;
constexpr int PAD = 15;            // PADDING_L
constexpr int NBC = 8192;          // B*C = t-stride in elements; (b,c) contiguous
constexpr int BLOCK = 256;         // 4 waves
constexpr int TPT = 16;            // t-outputs per thread
constexpr int WIN = TPT + K - 1;   // 46 row window, float2 each
constexpr int CPB = 64;            // cols per block == one head (taps block-uniform)
constexpr int TRB = 128;           // t-rows per block (8 t-groups x 16)

typedef __attribute__((ext_vector_type(2))) float f32x2;

// Forced-in-flight 8B load: volatile asm the register allocator cannot split
// or re-serialize. 46 of these per thread = 23.5 KB in flight per wave.
__device__ __forceinline__ f32x2 aload2(const float* p) {
    f32x2 r;
    asm volatile("global_load_dwordx2 %0, %1, off" : "=v"(r) : "v"(p));
    return r;
}

// One tap: KK compile-time; wk is an SGPR (block-uniform), xv statically indexed.
template <int KK>
__device__ __forceinline__ void tap(f32x2 (&acc)[TPT], const f32x2 (&xv)[WIN], float wk) {
#pragma unroll
    for (int i = 0; i < TPT; ++i) {
        acc[i].x = fmaf(wk, xv[i + KK].x, acc[i].x);
        acc[i].y = fmaf(wk, xv[i + KK].y, acc[i].y);
    }
}
template <int... Ks>
__device__ __forceinline__ void all_taps(f32x2 (&acc)[TPT], const f32x2 (&xv)[WIN],
                                         const float (&w)[K],
                                         std::integer_sequence<int, Ks...>) {
    (tap<Ks>(acc, xv, w[Ks]), ...);
}

// Tiny prelude kernel: per-head softmax of the 31 taps -> wtab[head*32 + k]
__global__ __launch_bounds__(64) void softmax_w_kernel(const float* __restrict__ wgt,
                                                       float* __restrict__ wtab) {
    const int head = blockIdx.x;
    const int lane = threadIdx.x;
    float raw = (lane < K) ? wgt[head * K + lane] : -INFINITY;
    float m = raw;
#pragma unroll
    for (int off = 32; off >= 1; off >>= 1) m = fmaxf(m, __shfl_xor(m, off));
    float e = (lane < K) ? expf(raw - m) : 0.0f;
    float s = e;
#pragma unroll
    for (int off = 32; off >= 1; off >>= 1) s += __shfl_xor(s, off);
    if (lane < 32) wtab[head * 32 + lane] = (lane < K) ? e / s : 0.0f;
}

__global__ __launch_bounds__(BLOCK, 3) void lconv_main(
    const float* __restrict__ x,      // (T, B, C)
    const float* __restrict__ bias,   // (C)
    const float* __restrict__ wtab,   // (16, 32) softmaxed taps, in d_ws
    const float* __restrict__ zbuf,   // zero region, in d_ws
    float* __restrict__ out)          // (T, B, C)
{
    const int tid  = threadIdx.x;
    const int cx   = tid & 31;          // float2 column group within the head
    const int ty   = tid >> 5;          // 0..7 t-group
    const int bc0  = blockIdx.x * CPB;  // head-aligned
    const int c0   = bc0 & (C - 1);
    const int head = c0 >> 6;           // block-uniform (blockIdx-derived)
    const int t0   = blockIdx.y * TRB + ty * TPT;
    const int tstart = t0 - PAD;

    // Block-uniform taps via scalar loads (lgkmcnt stream, independent of vmcnt)
    float w[K];
    const float* wp = wtab + head * 32;
#pragma unroll
    for (int k = 0; k < K; ++k) w[k] = wp[k];

    const f32x2 bias2 = *(const f32x2*)(bias + c0 + 2 * cx);

    // ---- 46 forced-in-flight 8B loads ----
    f32x2 xv[WIN];
    const float* base = x + (ptrdiff_t)tstart * NBC + bc0 + 2 * cx;
    if (blockIdx.y >= 1 && blockIdx.y <= 14) {        // interior strip: no OOB possible
#pragma unroll
        for (int j = 0; j < WIN; ++j)
            xv[j] = aload2(base + (ptrdiff_t)j * NBC);
    } else {                                          // edge strips: predicated pointer
        const float* zsrc = zbuf + 2 * cx;
#pragma unroll
        for (int j = 0; j < WIN; ++j) {
            const int tg = tstart + j;
            const float* p = ((unsigned)tg < (unsigned)T)
                               ? (base + (ptrdiff_t)j * NBC) : zsrc;
            xv[j] = aload2(p);
        }
    }

    // Single drain; fence so no FMA is hoisted above the wait (rule #18).
    asm volatile("s_waitcnt vmcnt(0)" ::: "memory");
    __builtin_amdgcn_sched_barrier(0);

    // ---- 31 x 16 x 2 FMAs, every index compile-time ----
    f32x2 acc[TPT];
#pragma unroll
    for (int i = 0; i < TPT; ++i) acc[i] = f32x2{0.0f, 0.0f};
    all_taps(acc, xv, w, std::make_integer_sequence<int, K>{});

    // ---- epilogue: bias + coalesced 256B/wave NT stores ----
    float* op = out + (ptrdiff_t)t0 * NBC + bc0 + 2 * cx;
#pragma unroll
    for (int i = 0; i < TPT; ++i) {
        const f32x2 v = acc[i] + bias2;
        __builtin_nontemporal_store(v, (f32x2*)(op + (ptrdiff_t)i * NBC));
    }
}

extern "C" void kernel_launch(void* const* d_in, const int* in_sizes, int n_in,
                              void* d_out, int out_size, void* d_ws, size_t ws_size,
                              hipStream_t stream) {
    const float* x    = (const float*)d_in[0];
    const float* wgt  = (const float*)d_in[1];
    const float* bias = (const float*)d_in[2];
    float* out        = (float*)d_out;
    float* wtab       = (float*)d_ws;            // 16 heads x 32 floats = 2 KB
    const float* zbuf = (const float*)d_ws + 512;  // zero region after wtab

    hipMemsetAsync(d_ws, 0, 8192, stream);       // zeroes wtab region + zbuf
    softmax_w_kernel<<<dim3(16), dim3(64), 0, stream>>>(wgt, wtab);

    dim3 grid(NBC / CPB, T / TRB);               // (128, 16) = 2048 blocks, 8192 waves
    lconv_main<<<grid, dim3(BLOCK), 0, stream>>>(x, bias, wtab, zbuf, out);
}

// Round 11
// 31.828 us; speedup vs baseline: 1.2643x; 1.1073x over previous
//
#include <hip/hip_runtime.h>
#include <utility>
#include <cmath>

// Problem constants (fixed by the reference setup)
constexpr int T = 2048;
constexpr int B = 8;
constexpr int C = 1024;
constexpr int H = 16;
constexpr int K = 31;
constexpr int PAD = 15;            // PADDING_L
constexpr int NBC = B * C;         // 8192 = t-stride in elements; (b,c) contiguous
constexpr int BLOCK = 256;         // 4 waves; each wave spans 64 bc -> one head
constexpr int TT = 32;             // t-outputs per thread
constexpr int WIN = TT + K - 1;    // 62-row register window (statically indexed)
constexpr int NXS = NBC / BLOCK;   // 32 bc-strips
constexpr int NYT = T / TT;        // 64 t-tiles per strip
constexpr int NXCD = 8;

// One tap: KK compile-time -> w[KK] stays in SGPR, xv[i+KK] statically-indexed reg.
template <int KK>
__device__ __forceinline__ void tap(float (&acc)[TT], const float (&xv)[WIN], float wk) {
#pragma unroll
    for (int i = 0; i < TT; ++i)
        acc[i] = fmaf(wk, xv[i + KK], acc[i]);
}

template <int... Ks>
__device__ __forceinline__ void all_taps(float (&acc)[TT], const float (&xv)[WIN],
                                         const float (&w)[K],
                                         std::integer_sequence<int, Ks...>) {
    (tap<Ks>(acc, xv, w[Ks]), ...);
}

// Broadcast tap k from lane k to all lanes as wave-uniform (SGPR) values,
// with compile-time lane indices (v_readlane_b32 with literal lane).
template <int... Ks>
__device__ __forceinline__ void bcast_taps(float (&w)[K], float v,
                                           std::integer_sequence<int, Ks...>) {
    ((w[Ks] = __int_as_float(__builtin_amdgcn_readlane(__float_as_int(v), Ks))), ...);
}

__global__ __launch_bounds__(BLOCK, 4) void lconv_tbc_kernel(
    const float* __restrict__ x,      // (T, B, C)
    const float* __restrict__ wgt,    // (H, 1, K)
    const float* __restrict__ bias,   // (C)
    float* __restrict__ out)          // (T, B, C)
{
    // ---- XCD-locality swizzle (bijective, 2048 = 8 xcd x 4 strips x 64 t-tiles).
    // Dispatcher round-robins wgid%8 across XCDs; invert so that ALL 64 t-tiles
    // of a bc-strip land on ONE XCD. A strip's full input column set is 2 MB ->
    // fits that XCD's 4 MB L2, so inter-tile halo re-reads hit L2, not L3.
    const int s    = blockIdx.x;
    const int xcd  = s & (NXCD - 1);
    const int pos  = s >> 3;              // 0..255 within this XCD's chunk
    const int xl   = pos >> 6;            // 0..3   local strip
    const int yt   = pos & (NYT - 1);     // 0..63  t-tile
    const int bx   = xcd * (NXS / NXCD) + xl;   // 0..31 bc-strip

    const int tid  = threadIdx.x;
    const int lane = tid & 63;
    const int bc   = bx * BLOCK + tid;    // contiguous per wave
    const int c    = bc & (C - 1);
    const int t0   = yt * TT;
    const int tstart = t0 - PAD;

    // ---- per-wave softmax of this wave's head (64 bc columns == one head) ----
    const int head = c >> 6;              // wave-uniform
    float raw = (lane < K) ? wgt[head * K + lane] : -INFINITY;
    float m = raw;
    #pragma unroll
    for (int off = 32; off >= 1; off >>= 1) m = fmaxf(m, __shfl_xor(m, off));
    float e = (lane < K) ? expf(raw - m) : 0.0f;
    float s1 = e;
    #pragma unroll
    for (int off = 32; off >= 1; off >>= 1) s1 += __shfl_xor(s1, off);
    const float myw = e / s1;             // lanes >= K hold 0

    float w[K];
    bcast_taps(w, myw, std::make_integer_sequence<int, K>{});   // 31x v_readlane -> SGPRs

    // ---- 62 coalesced loads into a statically-indexed register window ----
    float xv[WIN];
    if (tstart >= 0 && tstart + WIN <= T) {
        const float* rowp = x + (size_t)tstart * NBC;
        #pragma unroll
        for (int j = 0; j < WIN; ++j)
            xv[j] = rowp[(size_t)j * NBC + bc];
    } else {
        #pragma unroll
        for (int j = 0; j < WIN; ++j) {
            const int tg = tstart + j;
            xv[j] = ((unsigned)tg < (unsigned)T) ? x[(size_t)tg * NBC + bc] : 0.0f;
        }
    }

    __builtin_amdgcn_sched_barrier(0);

    // ---- 31 x 32 FMAs, every index compile-time ----
    float acc[TT];
    #pragma unroll
    for (int i = 0; i < TT; ++i) acc[i] = 0.0f;
    all_taps(acc, xv, w, std::make_integer_sequence<int, K>{});

    // ---- epilogue: bias + coalesced nontemporal stores (don't pollute L2) ----
    const float bb = bias[c];
    float* op = out + (size_t)t0 * NBC + bc;
    #pragma unroll
    for (int i = 0; i < TT; ++i)
        __builtin_nontemporal_store(acc[i] + bb, &op[(size_t)i * NBC]);
}

extern "C" void kernel_launch(void* const* d_in, const int* in_sizes, int n_in,
                              void* d_out, int out_size, void* d_ws, size_t ws_size,
                              hipStream_t stream) {
    const float* x    = (const float*)d_in[0];
    const float* wgt  = (const float*)d_in[1];
    const float* bias = (const float*)d_in[2];
    float* out        = (float*)d_out;

    dim3 grid(NXS * NYT);   // 2048 blocks, 1-D, swizzled in-kernel; no barriers
    lconv_tbc_kernel<<<grid, dim3(BLOCK), 0, stream>>>(x, wgt, bias, out);
}